// Round 1
// baseline (199.646 us; speedup 1.0000x reference)
//
#include <hip/hip_runtime.h>

// out[pid] = verified_id[NUM_DRAFT * pid + accept_lens[pid] - 1]
// BS = 2,097,152, NUM_DRAFT = 16.
// Memory-bound gather. 4 outputs per thread: int4 load of lens, 4 scalar
// gathers (unavoidable: 4B each from distinct 64B rows), float4 store.

#define NUM_DRAFT 16

__global__ __launch_bounds__(256) void gather_verified(
        const float* __restrict__ verified_id,
        const int*   __restrict__ accept_lens,
        float*       __restrict__ out,
        int bs4 /* bs/4 */) {
    int t = blockIdx.x * blockDim.x + threadIdx.x;
    if (t >= bs4) return;
    int pid0 = t << 2;

    const int4 l = *reinterpret_cast<const int4*>(accept_lens + pid0);

    // row base for pid0: 16*pid0; rows are 16 floats apart
    long base = (long)pid0 << 4;  // NUM_DRAFT * pid0
    float4 o;
    o.x = verified_id[base +  0 + (l.x - 1)];
    o.y = verified_id[base + 16 + (l.y - 1)];
    o.z = verified_id[base + 32 + (l.z - 1)];
    o.w = verified_id[base + 48 + (l.w - 1)];

    *reinterpret_cast<float4*>(out + pid0) = o;
}

extern "C" void kernel_launch(void* const* d_in, const int* in_sizes, int n_in,
                              void* d_out, int out_size, void* d_ws, size_t ws_size,
                              hipStream_t stream) {
    const float* verified_id = (const float*)d_in[0];
    const int*   accept_lens = (const int*)d_in[1];
    float*       out         = (float*)d_out;

    const int bs  = in_sizes[1];      // 2,097,152
    const int bs4 = bs >> 2;          // 524,288 threads
    const int block = 256;
    const int grid  = (bs4 + block - 1) / block;  // 2048 blocks

    gather_verified<<<grid, block, 0, stream>>>(verified_id, accept_lens, out, bs4);
}

// Round 2
// 195.497 us; speedup vs baseline: 1.0212x; 1.0212x over previous
//
#include <hip/hip_runtime.h>

// out[pid] = verified_id[16*pid + accept_lens[pid] - 1], BS = 2,097,152.
//
// R1 lesson: per-thread scalar gathers (lanes 256B apart) are uncoalesced —
// 64 cachelines per wave instruction. Since EVERY row of verified_id is
// touched (one element needed out of each 16-float row), the whole 128 MiB
// array must stream from HBM anyway. So: stream it COALESCED through LDS,
// then do the data-dependent pick from LDS where random access is cheap.
//
// Block = 256 threads = 256 pids = 256 rows = 16 KiB tile.
// Stage: thread t loads float4 #(t + 256k), k=0..3  -> consecutive lanes,
// consecutive 16B: perfect coalescing. Pick: lds[t*16 + len-1].

#define NUM_DRAFT 16

__global__ __launch_bounds__(256) void gather_verified_lds(
        const float* __restrict__ verified_id,
        const int*   __restrict__ accept_lens,
        float*       __restrict__ out) {
    __shared__ float tile[256 * NUM_DRAFT];  // 16 KiB

    const int t    = threadIdx.x;
    const int bpid = blockIdx.x * 256;           // first pid of this block

    // ---- coalesced stage: 256 rows = 4096 floats = 1024 float4 ----
    const float4* src4 = reinterpret_cast<const float4*>(verified_id) + (size_t)bpid * 4;
    float4* tile4 = reinterpret_cast<float4*>(tile);
#pragma unroll
    for (int k = 0; k < 4; ++k) {
        tile4[t + 256 * k] = src4[t + 256 * k];
    }

    // coalesced lens load (overlaps with staging latency)
    const int len = accept_lens[bpid + t];

    __syncthreads();

    // ---- data-dependent pick from LDS, coalesced store ----
    out[bpid + t] = tile[t * NUM_DRAFT + (len - 1)];
}

extern "C" void kernel_launch(void* const* d_in, const int* in_sizes, int n_in,
                              void* d_out, int out_size, void* d_ws, size_t ws_size,
                              hipStream_t stream) {
    const float* verified_id = (const float*)d_in[0];
    const int*   accept_lens = (const int*)d_in[1];
    float*       out         = (float*)d_out;

    const int bs   = in_sizes[1];       // 2,097,152
    const int grid = bs / 256;          // 8192 blocks

    gather_verified_lds<<<grid, 256, 0, stream>>>(verified_id, accept_lens, out);
}